// Round 7
// baseline (132.316 us; speedup 1.0000x reference)
//
#include <hip/hip_runtime.h>

// ResidualBlock2 (AdderNet): two adder-convs + BN + ReLU + residual.
// N=32, C=32, H=W=32, K=3. No multiplies -> no MFMA; pure VALU
// (sub + add-with-abs-modifier per contribution; floor ~7.7us/conv).
// R7: latency-first design. 1 block/CU (grid 256), whole x tile resident
// (xs[32][18][36], 83KB), lane = 2co x 8-col strip (P=16), explicit 2-deep
// register double-buffer on the ci loop (named reg sets, no runtime-indexed
// arrays), single staging barrier. LDS reads: 3x(b128,b128,b64) x-window +
// 4xb128+b64 weights per ci = 14 instr / 288 VALU -> VALU-bound on paper.

#define QSCALE (2.5f / 127.f)

__device__ __forceinline__ float quantf(float w) {
  float v = rintf(w * (1.0f / QSCALE));     // round-half-even = jnp.round
  v = fminf(fmaxf(v, -127.f), 127.f);
  return v * QSCALE;
}

// quantize + pack: WQ[(ci*9+tap)*32 + co] = quant(w[co][ci*9+tap])
__global__ __launch_bounds__(256) void quant_k(const float* __restrict__ w1,
                                               const float* __restrict__ w2,
                                               float* __restrict__ q1,
                                               float* __restrict__ q2) {
  int i = blockIdx.x * 256 + threadIdx.x;
  if (i >= 18432) return;
  const float* w = (i < 9216) ? w1 : w2;
  float* dst = (i < 9216) ? q1 : q2;
  int j = (i < 9216) ? i : i - 9216;
  int co = j / 288;
  int r = j - co * 288;                     // r = ci*9 + tap
  dst[r * 32 + co] = quantf(w[j]);
}

// Grid 256 = 32 n x 2 row-halves(16 rows) x 4 co-groups(8 co). 1 block/CU.
// Block 256 thr = 4 waves; wave wv owns co pair cg*8 + 2wv + {0,1}.
// Lane l: qd = l&3 (cols 8qd..8qd+7), R = l>>2 (row h0+R). P=16 out/lane.
template <bool AFFINE>
__global__ __launch_bounds__(256, 1) void conv_k(
    const float* __restrict__ in,       // [32][32][32][32] conv input
    const float* __restrict__ wq,       // packed [288][32] this conv
    const float* __restrict__ ps_prev,  // [32][64] prev partial sums (or null)
    const float* __restrict__ pq_prev,  // [32][64] prev partial sumsq
    const float* __restrict__ wq_prev,  // packed prev weights (for wb)
    const float* __restrict__ gprev,    // prev gamma
    const float* __restrict__ bprev,    // prev beta
    float* __restrict__ outb,           // raw conv out
    float* __restrict__ ps_out,         // [32][64]  idx: co*64 + n*2 + rh
    float* __restrict__ pq_out) {
  __shared__ __align__(16) float xs[32 * 18 * 36];   // 82944 B
  __shared__ __align__(16) float wls[32 * 4 * 20];   // 10240 B
  __shared__ float r2a[32][8], r2b[32][8], r2c[32][8];
  __shared__ float abuf[32], bbuf[32];

  const int tid = threadIdx.x;
  const int blk = blockIdx.x;
  const int n = blk >> 3, rh = (blk >> 2) & 1, cg = blk & 3;
  const int h0 = rh << 4;

  if (AFFINE) {
    // Redundant per-block BN1 fold: a=g/sqrt(var+eps), b = beta + wb - a*mu.
    const int c = tid & 31, ch = tid >> 5;           // ch 0..7
    float s = 0.f, qv = 0.f;
    #pragma unroll
    for (int j = 0; j < 8; ++j) {
      s += ps_prev[c * 64 + ch * 8 + j];
      qv += pq_prev[c * 64 + ch * 8 + j];
    }
    float wbp = 0.f;
    #pragma unroll 4
    for (int u = 0; u < 36; ++u) wbp += fabsf(wq_prev[(ch * 36 + u) * 32 + c]);
    r2a[c][ch] = s; r2b[c][ch] = qv; r2c[c][ch] = wbp;
    __syncthreads();
    if (tid < 32) {
      double S = 0.0, Q = 0.0; float W = 0.f;
      #pragma unroll
      for (int k = 0; k < 8; ++k) {
        S += (double)r2a[tid][k]; Q += (double)r2b[tid][k]; W += r2c[tid][k];
      }
      const double M = 32768.0;
      const double mu = S / M;
      const double var = Q / M - mu * mu;
      const double inv = 1.0 / sqrt(var + 1e-5);
      const double g = (double)gprev[tid];
      abuf[tid] = (float)(g * inv);
      bbuf[tid] = (float)((double)bprev[tid] + (double)(W * (1.f / 288.f)) - g * inv * mu);
    }
    __syncthreads();
  }

  // ---- stage weights: wls[(ci*4+wv)*20 + tap*2 + p] = wq[(ci*9+tap)*32 + cg*8+2wv+p]
  for (int i = tid; i < 2560; i += 256) {
    const int pc = i / 20, t = i - pc * 20;
    float v = 0.f;
    if (t < 18) {
      const int ci = pc >> 2, wv2 = pc & 3;
      const int tap = t >> 1, p = t & 1;
      v = wq[(ci * 9 + tap) * 32 + cg * 8 + wv2 * 2 + p];
    }
    wls[i] = v;
  }
  // ---- stage x: xs[ci*648 + sr*36 + c], sr 0..17 <-> row h0-1+sr,
  // c 0..35 <-> global col c-1 (zero-padded outside).
  for (int i = tid; i < 20736; i += 256) {
    const int ci = i / 648;
    const int rem = i - ci * 648;
    const int sr = rem / 36, c = rem - sr * 36;
    const int h = h0 - 1 + sr, wcol = c - 1;
    float v = 0.f;
    if ((unsigned)h < 32u && (unsigned)wcol < 32u) {
      v = in[((n * 32 + ci) * 32 + h) * 32 + wcol];
      if (AFFINE) v = fmaxf(fmaf(abuf[ci], v, bbuf[ci]), 0.f);
    }
    xs[i] = v;
  }
  __syncthreads();

  const int l = tid & 63, wv = tid >> 6;
  const int qd = l & 3, R = l >> 2;
  const float* xbase = xs + R * 36 + 8 * qd;
  const float* wbase = wls + wv * 20;

  float xc[3][10], xn[3][10], wc[18], wn[18];
  float a0[8] = {0.f, 0.f, 0.f, 0.f, 0.f, 0.f, 0.f, 0.f};
  float a1[8] = {0.f, 0.f, 0.f, 0.f, 0.f, 0.f, 0.f, 0.f};

  auto LDX = [&](float d[3][10], int ci) {
    const float* p = xbase + ci * 648;
    #pragma unroll
    for (int rr = 0; rr < 3; ++rr) {
      const float4 A = *(const float4*)(p + rr * 36);
      const float4 B = *(const float4*)(p + rr * 36 + 4);
      const float2 C = *(const float2*)(p + rr * 36 + 8);
      d[rr][0] = A.x; d[rr][1] = A.y; d[rr][2] = A.z; d[rr][3] = A.w;
      d[rr][4] = B.x; d[rr][5] = B.y; d[rr][6] = B.z; d[rr][7] = B.w;
      d[rr][8] = C.x; d[rr][9] = C.y;
    }
  };
  auto LDW = [&](float d[18], int ci) {
    const float* p = wbase + ci * 80;
    const float4 W0 = *(const float4*)(p);
    const float4 W1 = *(const float4*)(p + 4);
    const float4 W2 = *(const float4*)(p + 8);
    const float4 W3 = *(const float4*)(p + 12);
    const float2 W4 = *(const float2*)(p + 16);
    d[0] = W0.x; d[1] = W0.y; d[2] = W0.z; d[3] = W0.w;
    d[4] = W1.x; d[5] = W1.y; d[6] = W1.z; d[7] = W1.w;
    d[8] = W2.x; d[9] = W2.y; d[10] = W2.z; d[11] = W2.w;
    d[12] = W3.x; d[13] = W3.y; d[14] = W3.z; d[15] = W3.w;
    d[16] = W4.x; d[17] = W4.y;
  };
  auto CMP = [&](const float x[3][10], const float w[18]) {
    #pragma unroll
    for (int kh = 0; kh < 3; ++kh) {
      #pragma unroll
      for (int kw = 0; kw < 3; ++kw) {
        const float wa = w[(kh * 3 + kw) * 2];
        const float wb = w[(kh * 3 + kw) * 2 + 1];
        #pragma unroll
        for (int j = 0; j < 8; ++j) {
          const float xv = x[kh][j + kw];
          a0[j] += fabsf(xv - wa);
          a1[j] += fabsf(xv - wb);
        }
      }
    }
  };

  LDX(xc, 0); LDW(wc, 0);
  #pragma unroll 1
  for (int ci = 0; ci < 30; ci += 2) {
    LDX(xn, ci + 1); LDW(wn, ci + 1);
    CMP(xc, wc);
    LDX(xc, ci + 2); LDW(wc, ci + 2);
    CMP(xn, wn);
  }
  LDX(xn, 31); LDW(wn, 31);
  CMP(xc, wc);
  CMP(xn, wn);

  // ---- epilogue: stores (2x float4 per co) + per-(co,block) stats
  const int row = h0 + R;
  {
    const int co = cg * 8 + wv * 2;
    float* op = outb + (((n * 32 + co) * 32 + row) * 32 + 8 * qd);
    float4 s0, s1;
    s0.x = -a0[0]; s0.y = -a0[1]; s0.z = -a0[2]; s0.w = -a0[3];
    s1.x = -a0[4]; s1.y = -a0[5]; s1.z = -a0[6]; s1.w = -a0[7];
    *(float4*)op = s0; *(float4*)(op + 4) = s1;
    float s = s0.x + s0.y + s0.z + s0.w + s1.x + s1.y + s1.z + s1.w;
    float qv = s0.x*s0.x + s0.y*s0.y + s0.z*s0.z + s0.w*s0.w +
               s1.x*s1.x + s1.y*s1.y + s1.z*s1.z + s1.w*s1.w;
    #pragma unroll
    for (int d = 32; d; d >>= 1) { s += __shfl_xor(s, d); qv += __shfl_xor(qv, d); }
    if (l == 0) { ps_out[co * 64 + (blk >> 2)] = s; pq_out[co * 64 + (blk >> 2)] = qv; }
  }
  {
    const int co = cg * 8 + wv * 2 + 1;
    float* op = outb + (((n * 32 + co) * 32 + row) * 32 + 8 * qd);
    float4 s0, s1;
    s0.x = -a1[0]; s0.y = -a1[1]; s0.z = -a1[2]; s0.w = -a1[3];
    s1.x = -a1[4]; s1.y = -a1[5]; s1.z = -a1[6]; s1.w = -a1[7];
    *(float4*)op = s0; *(float4*)(op + 4) = s1;
    float s = s0.x + s0.y + s0.z + s0.w + s1.x + s1.y + s1.z + s1.w;
    float qv = s0.x*s0.x + s0.y*s0.y + s0.z*s0.z + s0.w*s0.w +
               s1.x*s1.x + s1.y*s1.y + s1.z*s1.z + s1.w*s1.w;
    #pragma unroll
    for (int d = 32; d; d >>= 1) { s += __shfl_xor(s, d); qv += __shfl_xor(qv, d); }
    if (l == 0) { ps_out[co * 64 + (blk >> 2)] = s; pq_out[co * 64 + (blk >> 2)] = qv; }
  }
}

// ---- K3: redundant BN2 fold + relu(a2*o2 + b2 + x) ----
__global__ __launch_bounds__(256) void final_k(
    const float* __restrict__ o2, const float* __restrict__ xres,
    const float* __restrict__ ps, const float* __restrict__ pq,
    const float* __restrict__ wq2, const float* __restrict__ g2,
    const float* __restrict__ b2, float* __restrict__ out) {
  __shared__ float r2a[32][8], r2b[32][8], r2c[32][8];
  __shared__ float abuf[32], bbuf[32];
  const int tid = threadIdx.x;
  const int c = tid & 31, ch = tid >> 5;
  float s = 0.f, qv = 0.f;
  #pragma unroll
  for (int j = 0; j < 8; ++j) {
    s += ps[c * 64 + ch * 8 + j];
    qv += pq[c * 64 + ch * 8 + j];
  }
  float wbp = 0.f;
  #pragma unroll 4
  for (int u = 0; u < 36; ++u) wbp += fabsf(wq2[(ch * 36 + u) * 32 + c]);
  r2a[c][ch] = s; r2b[c][ch] = qv; r2c[c][ch] = wbp;
  __syncthreads();
  if (tid < 32) {
    double S = 0.0, Q = 0.0; float W = 0.f;
    #pragma unroll
    for (int k = 0; k < 8; ++k) {
      S += (double)r2a[tid][k]; Q += (double)r2b[tid][k]; W += r2c[tid][k];
    }
    const double M = 32768.0;
    const double mu = S / M;
    const double var = Q / M - mu * mu;
    const double inv = 1.0 / sqrt(var + 1e-5);
    const double g = (double)g2[tid];
    abuf[tid] = (float)(g * inv);
    bbuf[tid] = (float)((double)b2[tid] + (double)(W * (1.f / 288.f)) - g * inv * mu);
  }
  __syncthreads();

  const int base = blockIdx.x * 512;  // float4 units; 512 x 512 = 262144
  for (int i = tid; i < 512; i += 256) {
    const int f4 = base + i;
    const int cc = (f4 >> 8) & 31;
    const float4 o = ((const float4*)o2)[f4];
    const float4 xr = ((const float4*)xres)[f4];
    const float av = abuf[cc], bv = bbuf[cc];
    float4 r;
    r.x = fmaxf(fmaf(av, o.x, bv) + xr.x, 0.f);
    r.y = fmaxf(fmaf(av, o.y, bv) + xr.y, 0.f);
    r.z = fmaxf(fmaf(av, o.z, bv) + xr.z, 0.f);
    r.w = fmaxf(fmaf(av, o.w, bv) + xr.w, 0.f);
    ((float4*)out)[f4] = r;
  }
}

extern "C" void kernel_launch(void* const* d_in, const int* in_sizes, int n_in,
                              void* d_out, int out_size, void* d_ws, size_t ws_size,
                              hipStream_t stream) {
  const float* x   = (const float*)d_in[0];
  const float* w1  = (const float*)d_in[1];
  const float* g1  = (const float*)d_in[2];
  const float* be1 = (const float*)d_in[3];
  const float* w2  = (const float*)d_in[4];
  const float* g2  = (const float*)d_in[5];
  const float* be2 = (const float*)d_in[6];
  float* ws = (float*)d_ws;

  float* WQ1 = ws;                  // 9216  (packed [288][32])
  float* WQ2 = ws + 9216;           // 9216
  float* PS1 = ws + 18432;          // [32][64] = 2048
  float* PQ1 = ws + 20480;          // 2048
  float* PS2 = ws + 22528;          // 2048
  float* PQ2 = ws + 24576;          // 2048
  float* O1  = ws + 26624;          // 1048576 (16B aligned)
  float* O2  = O1 + 1048576;        // 1048576
  float* out = (float*)d_out;

  quant_k<<<72, 256, 0, stream>>>(w1, w2, WQ1, WQ2);
  conv_k<false><<<256, 256, 0, stream>>>(x, WQ1, nullptr, nullptr, nullptr,
                                         nullptr, nullptr, O1, PS1, PQ1);
  conv_k<true><<<256, 256, 0, stream>>>(O1, WQ2, PS1, PQ1, WQ1, g1, be1,
                                        O2, PS2, PQ2);
  final_k<<<512, 256, 0, stream>>>(O2, x, PS2, PQ2, WQ2, g2, be2, out);
}

// Round 8
// 78.473 us; speedup vs baseline: 1.6861x; 1.6861x over previous
//
#include <hip/hip_runtime.h>

// ResidualBlock2 (AdderNet): two adder-convs + BN + ReLU + residual.
// N=32, C=32, H=W=32, K=3. No multiplies -> no MFMA; pure VALU
// (2 instr per |x-w|; floor ~7.7us/conv).
// R8: occupancy experiment. R1's proven inner loop (9 bcast b128 weight
// reads + 9 b32 x reads + 72 VALU per wave-ci) but 4 co/wave instead of 8:
// block = 512 thr / 8 waves (all on one 2-row x 32-col position set,
// wave v -> co quad 4v), grid 512, 2 blocks/CU => 16 waves/CU = 4/SIMD
// (R1-R7 never exceeded 2/SIMD; R3-R6 all ~52us regardless of instr mix
// => latency-bound, so doubling waves/SIMD is the lever under test).

#define QSCALE (2.5f / 127.f)

__device__ __forceinline__ float quantf(float w) {
  float v = rintf(w * (1.0f / QSCALE));     // round-half-even = jnp.round
  v = fminf(fmaxf(v, -127.f), 127.f);
  return v * QSCALE;
}

// quantize + pack: WQ[(ci*9+tap)*32 + co] = quant(w[co][ci*9+tap])
__global__ __launch_bounds__(256) void quant_k(const float* __restrict__ w1,
                                               const float* __restrict__ w2,
                                               float* __restrict__ q1,
                                               float* __restrict__ q2) {
  int i = blockIdx.x * 256 + threadIdx.x;
  if (i >= 18432) return;
  const float* w = (i < 9216) ? w1 : w2;
  float* dst = (i < 9216) ? q1 : q2;
  int j = (i < 9216) ? i : i - 9216;
  int co = j / 288;
  int r = j - co * 288;                     // r = ci*9 + tap
  dst[r * 32 + co] = quantf(w[j]);
}

// Block = (n, row-pair): 512 thr = 8 waves; wave v -> co 4v..4v+3.
// Lane l: w = l&31 (col), hl = l>>5 (row in pair). 4 outputs/lane.
// Grid 512 = 32 n x 16 row-pairs; 2 blocks/CU => 16 waves/CU (4/SIMD).
template <bool AFFINE>
__global__ __launch_bounds__(512, 4) void conv_k(
    const float* __restrict__ in,       // [32][32][32][32] conv input
    const float* __restrict__ wq,       // packed [288][32] this conv
    const float* __restrict__ ps_prev,  // [512][32] prev partial sums (or null)
    const float* __restrict__ pq_prev,  // [512][32] prev partial sumsq
    const float* __restrict__ wq_prev,  // packed prev weights (for wb)
    const float* __restrict__ gprev,    // prev gamma
    const float* __restrict__ bprev,    // prev beta
    float* __restrict__ outb,           // raw conv out
    float* __restrict__ ps_out,         // [512][32]  idx: blk*32 + co
    float* __restrict__ pq_out) {
  __shared__ __align__(16) float xs[32][4][34];  // 17408 B, rows h0-1..h0+2
  __shared__ __align__(16) float wl[288 * 32];   // 36864 B
  __shared__ float r2a[32][8], r2b[32][8], r2c[32][8];
  __shared__ float abuf[32], bbuf[32];

  const int tid = threadIdx.x;
  const int blk = blockIdx.x;
  const int n = blk >> 4;
  const int h0 = (blk & 15) << 1;

  if (AFFINE) {
    // Redundant per-block BN1 fold (deterministic): a=g/sqrt(var+eps),
    // b = beta + wb - a*mu. Partials [512][32]: coalesced reads.
    if (tid < 256) {
      const int c = tid & 31, ch = tid >> 5;       // ch 0..7
      float s = 0.f, q = 0.f;
      const float* pp = ps_prev + ch * 64 * 32 + c;
      const float* qq = pq_prev + ch * 64 * 32 + c;
      #pragma unroll 4
      for (int i2 = 0; i2 < 64; ++i2) { s += pp[i2 * 32]; q += qq[i2 * 32]; }
      float wbp = 0.f;
      const float* wp = wq_prev + ch * 36 * 32 + c;
      #pragma unroll 4
      for (int u = 0; u < 36; ++u) wbp += fabsf(wp[u * 32]);
      r2a[c][ch] = s; r2b[c][ch] = q; r2c[c][ch] = wbp;
    }
    __syncthreads();
    if (tid < 32) {
      double S = 0.0, Q = 0.0; float W = 0.f;
      #pragma unroll
      for (int k = 0; k < 8; ++k) {
        S += (double)r2a[tid][k]; Q += (double)r2b[tid][k]; W += r2c[tid][k];
      }
      const double M = 32768.0;
      const double mu = S / M;
      const double var = Q / M - mu * mu;
      const double inv = 1.0 / sqrt(var + 1e-5);
      const double g = (double)gprev[tid];
      abuf[tid] = (float)(g * inv);
      bbuf[tid] = (float)((double)bprev[tid] + (double)(W * (1.f / 288.f)) - g * inv * mu);
    }
    __syncthreads();
  }

  // stage weights (flat float4 copy, coalesced)
  {
    const float4* src = (const float4*)wq;
    float4* dst = (float4*)wl;
    for (int i = tid; i < 2304; i += 512) dst[i] = src[i];
  }
  // stage x tile (rows h0-1..h0+2, cols -1..32), zero-padded; affine on conv2
  for (int i = tid; i < 4352; i += 512) {
    int ci = i / 136;
    int rem = i - ci * 136;
    int r = rem / 34, c = rem - r * 34;
    int h = h0 - 1 + r, w = c - 1;
    float v = 0.f;
    if ((unsigned)h < 32u && (unsigned)w < 32u) {
      v = in[((n * 32 + ci) * 32 + h) * 32 + w];
      if (AFFINE) v = fmaxf(fmaf(abuf[ci], v, bbuf[ci]), 0.f);
    }
    xs[ci][r][c] = v;
  }
  __syncthreads();

  const int l = tid & 63;
  const int w = l & 31, hl = l >> 5;
  const int v8 = tid >> 6;                  // wave id 0..7
  const int cb = v8 * 4;                    // co base (4 co per wave)

  float acc[4] = {0.f, 0.f, 0.f, 0.f};

  for (int ci = 0; ci < 32; ++ci) {
    const float* xr = &xs[ci][hl][w];
    const float* wrow = &wl[(ci * 9) * 32 + cb];
    #pragma unroll
    for (int kh = 0; kh < 3; ++kh) {
      const float x0 = xr[kh * 34 + 0];
      const float x1 = xr[kh * 34 + 1];
      const float x2 = xr[kh * 34 + 2];
      const float4 w0 = *(const float4*)(wrow + (kh * 3 + 0) * 32);
      const float4 w1 = *(const float4*)(wrow + (kh * 3 + 1) * 32);
      const float4 w2 = *(const float4*)(wrow + (kh * 3 + 2) * 32);
      acc[0] += fabsf(x0 - w0.x); acc[1] += fabsf(x0 - w0.y);
      acc[2] += fabsf(x0 - w0.z); acc[3] += fabsf(x0 - w0.w);
      acc[0] += fabsf(x1 - w1.x); acc[1] += fabsf(x1 - w1.y);
      acc[2] += fabsf(x1 - w1.z); acc[3] += fabsf(x1 - w1.w);
      acc[0] += fabsf(x2 - w2.x); acc[1] += fabsf(x2 - w2.y);
      acc[2] += fabsf(x2 - w2.z); acc[3] += fabsf(x2 - w2.w);
    }
  }

  // write raw conv out (per co: 64 consecutive floats per wave: coalesced)
  const int h = h0 + hl;
  #pragma unroll
  for (int jj = 0; jj < 4; ++jj) {
    const int co = cb + jj;
    const float o = -acc[jj];
    outb[((n * 32 + co) * 32 + h) * 32 + w] = o;
    float s = o, q = o * o;
    #pragma unroll
    for (int d = 32; d; d >>= 1) { s += __shfl_xor(s, d); q += __shfl_xor(q, d); }
    if (l == 0) { ps_out[blk * 32 + co] = s; pq_out[blk * 32 + co] = q; }
  }
}

// ---- K4: redundant BN2 fold + relu(a2*o2 + b2 + x) ----
__global__ __launch_bounds__(256) void final_k(
    const float* __restrict__ o2, const float* __restrict__ xres,
    const float* __restrict__ ps, const float* __restrict__ pq,
    const float* __restrict__ wq2, const float* __restrict__ g2,
    const float* __restrict__ b2, float* __restrict__ out) {
  __shared__ float r2a[32][8], r2b[32][8], r2c[32][8];
  __shared__ float abuf[32], bbuf[32];
  const int tid = threadIdx.x;
  const int c = tid & 31, ch = tid >> 5;
  float s = 0.f, q = 0.f;
  const float* pp = ps + ch * 64 * 32 + c;
  const float* qq = pq + ch * 64 * 32 + c;
  #pragma unroll 4
  for (int i2 = 0; i2 < 64; ++i2) { s += pp[i2 * 32]; q += qq[i2 * 32]; }
  float wbp = 0.f;
  const float* wp = wq2 + ch * 36 * 32 + c;
  #pragma unroll 4
  for (int u = 0; u < 36; ++u) wbp += fabsf(wp[u * 32]);
  r2a[c][ch] = s; r2b[c][ch] = q; r2c[c][ch] = wbp;
  __syncthreads();
  if (tid < 32) {
    double S = 0.0, Q = 0.0; float W = 0.f;
    #pragma unroll
    for (int k = 0; k < 8; ++k) {
      S += (double)r2a[tid][k]; Q += (double)r2b[tid][k]; W += r2c[tid][k];
    }
    const double M = 32768.0;
    const double mu = S / M;
    const double var = Q / M - mu * mu;
    const double inv = 1.0 / sqrt(var + 1e-5);
    const double g = (double)g2[tid];
    abuf[tid] = (float)(g * inv);
    bbuf[tid] = (float)((double)b2[tid] + (double)(W * (1.f / 288.f)) - g * inv * mu);
  }
  __syncthreads();

  const int base = blockIdx.x * 512;  // float4 units; 512 x 512 = 262144
  for (int i = tid; i < 512; i += 256) {
    const int f4 = base + i;
    const int cc = (f4 >> 8) & 31;
    const float4 o = ((const float4*)o2)[f4];
    const float4 xr = ((const float4*)xres)[f4];
    const float av = abuf[cc], bv = bbuf[cc];
    float4 r;
    r.x = fmaxf(fmaf(av, o.x, bv) + xr.x, 0.f);
    r.y = fmaxf(fmaf(av, o.y, bv) + xr.y, 0.f);
    r.z = fmaxf(fmaf(av, o.z, bv) + xr.z, 0.f);
    r.w = fmaxf(fmaf(av, o.w, bv) + xr.w, 0.f);
    ((float4*)out)[f4] = r;
  }
}

extern "C" void kernel_launch(void* const* d_in, const int* in_sizes, int n_in,
                              void* d_out, int out_size, void* d_ws, size_t ws_size,
                              hipStream_t stream) {
  const float* x   = (const float*)d_in[0];
  const float* w1  = (const float*)d_in[1];
  const float* g1  = (const float*)d_in[2];
  const float* be1 = (const float*)d_in[3];
  const float* w2  = (const float*)d_in[4];
  const float* g2  = (const float*)d_in[5];
  const float* be2 = (const float*)d_in[6];
  float* ws = (float*)d_ws;

  float* WQ1 = ws;                  // 9216  (packed [288][32])
  float* WQ2 = ws + 9216;           // 9216
  float* PS1 = ws + 18432;          // [512][32] = 16384
  float* PQ1 = ws + 34816;          // 16384
  float* PS2 = ws + 51200;          // 16384
  float* PQ2 = ws + 67584;          // 16384
  float* O1  = ws + 83968;          // 1048576 (16B aligned)
  float* O2  = O1 + 1048576;        // 1048576
  float* out = (float*)d_out;

  quant_k<<<72, 256, 0, stream>>>(w1, w2, WQ1, WQ2);
  conv_k<false><<<512, 512, 0, stream>>>(x, WQ1, nullptr, nullptr, nullptr,
                                         nullptr, nullptr, O1, PS1, PQ1);
  conv_k<true><<<512, 512, 0, stream>>>(O1, WQ2, PS1, PQ1, WQ1, g1, be1,
                                        O2, PS2, PQ2);
  final_k<<<512, 256, 0, stream>>>(O2, x, PS2, PQ2, WQ2, g2, be2, out);
}